// Round 15
// baseline (155.421 us; speedup 1.0000x reference)
//
#include <hip/hip_runtime.h>
#include <hip/hip_bf16.h>

// SupervisedGraphSage forward. fp32 device buffers; bf16 MFMA internally.
//   z  = x @ W1^T                        [N, D]  (K1)
//   h1 = leaky((z[neigh1].sum + z)/6)    [N, D]  (K2, only referenced rows)
//   h2 = leaky((h1[neigh2].sum+h1[nodes])/11 @ W2^T); out = h2 @ Wc^T  (K3 fused)
//
// R15: K1 re-tiled for BLOCK-LEVEL latency hiding. R14 (128.8us) left K1 at
// ~77us vs ~40 floor with 2 blocks/CU. Now 256-thr blocks, BM=64, BK=32:
// LDS = 2x16KB B-dbuf = 32KB (epilogue 64-row tile reuses it exactly) ->
// 4 blocks/CU at the same ~100 VGPR (4 waves/SIMD cap respected, R10 lesson).
// Wave-private A (R14-proven), counted vmcnt, W1 4-chunk swizzle (R10-proven).

#define NN 100000
#define FF 512
#define DD 256
#define BB 16384
#define CC 40

typedef __attribute__((ext_vector_type(8))) short bf16x8;
typedef __attribute__((ext_vector_type(4))) float f32x4;
typedef unsigned short u16;
typedef unsigned int u32;
typedef __attribute__((ext_vector_type(4))) u32 u32x4;

__device__ __forceinline__ float bf_lo(u32 u) { u32 v = u << 16; float f; __builtin_memcpy(&f, &v, 4); return f; }
__device__ __forceinline__ float bf_hi(u32 u) { u32 v = u & 0xffff0000u; float f; __builtin_memcpy(&f, &v, 4); return f; }
__device__ __forceinline__ float2 bf2f(u32 u) { return make_float2(bf_lo(u), bf_hi(u)); }
__device__ __forceinline__ float asf(u32 u) { float f; __builtin_memcpy(&f, &u, 4); return f; }
__device__ __forceinline__ u32 packbf2(float a, float b) {
  __hip_bfloat162 h = __float22bfloat162_rn(make_float2(a, b));
  u32 u; __builtin_memcpy(&u, &h, 4); return u;
}
__device__ __forceinline__ u16 fbits(float v) {
  __hip_bfloat16 h = __float2bfloat16(v);
  u16 u; __builtin_memcpy(&u, &h, 2); return u;
}
__device__ __forceinline__ float lrelu(float v) { return v >= 0.f ? v : 0.2f * v; }
// [R][64]-bf16 tile: byte offset of chunk c in row r, XOR-swizzled (G4). K3 use.
__device__ __forceinline__ int swz(int r, int c) { return r * 128 + ((c ^ (r & 7)) << 4); }
// direct global->LDS 16B copy (dest = wave-uniform base + lane*16)
__device__ __forceinline__ void gld_lds16(const u16* g, void* l) {
  __builtin_amdgcn_global_load_lds((const __attribute__((address_space(1))) unsigned int*)g,
                                   (__attribute__((address_space(3))) unsigned int*)l, 16, 0, 0);
}
__device__ __forceinline__ u32x4 ld4(const float* p) { return *(const u32x4*)p; }

// ---------------------------------------------------------------- K0
// W1 -> bf16 with 4-chunk-group swizzle (^(r&3), matches K1 BK=32 staging;
// R10-proven mapping). W2/Wc -> bf16 with 8-chunk swizzle (^(r&7)) for K3.
__global__ __launch_bounds__(256) void k0_cvt(
    const float* __restrict__ W1, const float* __restrict__ W2, const float* __restrict__ Wc,
    u16* __restrict__ w1b, u16* __restrict__ w2b, u16* __restrict__ wcb,
    u32* __restrict__ flagw)
{
  const int i = blockIdx.x * 256 + threadIdx.x;
  if (i < 25024) flagw[i] = 0;   // 100096 flag bytes
  if (i < 16384) {               // W1 [256][512]: r = i>>6, 16B-chunk cc = i&63
    const int r = i >> 6, cc = i & 63;
    const int lc = (cc & ~3) | ((cc ^ r) & 3);   // logical chunk at phys cc
    const float* s = W1 + (u32)r * 512 + (u32)lc * 8;
    const float4 v0 = *(const float4*)s;
    const float4 v1 = *(const float4*)(s + 4);
    uint4 o;
    o.x = packbf2(v0.x, v0.y); o.y = packbf2(v0.z, v0.w);
    o.z = packbf2(v1.x, v1.y); o.w = packbf2(v1.z, v1.w);
    *(uint4*)(w1b + (u32)r * 512 + (u32)cc * 8) = o;
    return;
  }
  const float* src; u16* dst; int r, cc;
  if (i < 24576)      { int j = i - 16384; src = W2; dst = w2b; r = j >> 5; cc = j & 31; }
  else if (i < 25856) { int j = i - 24576; src = Wc; dst = wcb; r = j >> 5; cc = j & 31; }
  else return;
  const int g = cc >> 3, cp = cc & 7;
  const float* s = src + (u32)r * 256 + g * 64 + (u32)(cp ^ (r & 7)) * 8;
  const float4 v0 = *(const float4*)s;
  const float4 v1 = *(const float4*)(s + 4);
  uint4 o;
  o.x = packbf2(v0.x, v0.y); o.y = packbf2(v0.z, v0.w);
  o.z = packbf2(v1.x, v1.y); o.w = packbf2(v1.z, v1.w);
  *(uint4*)(dst + (u32)r * 256 + g * 64 + cp * 8) = o;
}

// ---------------------------------------------------------------- K0b
__global__ __launch_bounds__(256) void k0b_flags(
    const int* __restrict__ nodes, const int* __restrict__ neigh2,
    unsigned char* __restrict__ flags)
{
  const int i = blockIdx.x * 256 + threadIdx.x;
  int idx;
  if (i < BB) idx = nodes[i];
  else if (i < BB + BB * 10) idx = neigh2[i - BB];
  else return;
  flags[idx] = 1;
}

// ---------------------------------------------------------------- K1
// z = x @ W1^T. BM=64, BN=256, BK=32, 16 steps, 256 thr = 4 waves.
// Wave w owns x-rows rowBase + w*16 + (lane&15) (private A, direct global
// loads: lane (lr,kg) reads x[row][ks*32+kg*8..+8] = the MFMA fragment).
// B: [256][32]bf16 LDS dbuf @0/@16384 via gld_lds from 4-chunk-swizzled w1b,
// counted vmcnt. Barriers guard only B. Epilogue: 32KB swizzled tile reused.
__global__ __launch_bounds__(256, 4) void k1_gemm(
    const float* __restrict__ x, const u16* __restrict__ w1b, u16* __restrict__ z)
{
  __shared__ __align__(16) unsigned char lds[32768];  // B0 @0, B1 @16384; epi reuses

  const int t = threadIdx.x;
  const int rowBase = blockIdx.x * 64;
  const int lane = t & 63, w = t >> 6;
  const int lr = lane & 15, kg = lane >> 4;

  // private A row for this lane
  int rw = rowBase + w * 16 + lr; if (rw > NN - 1) rw = NN - 1;
  const float* xr = x + (u32)rw * FF + (u32)kg * 8;

  // B staging: issue i covers rows i*64 + w*16 + (lane>>2), phys chunk lane&3
  const u32 bofs = (u32)(w * 16 + (lane >> 2)) * FF + (u32)(lane & 3) * 8;

  // fragment base: row = n*16+lr -> phys chunk kg^(row&3) = kg^(lr&3)
  const int bvb = lr * 64 + ((kg ^ (lr & 3)) << 4);   // + n*1024 + buf

  f32x4 acc[16];
#pragma unroll
  for (int n = 0; n < 16; ++n) acc[n] = (f32x4)0.0f;

  // prologue: A[0] (2 loads), B[0] -> buf0 (4), B[1] -> buf1 (4)
  u32x4 pa[2];
  pa[0] = ld4(xr);
  pa[1] = ld4(xr + 4);
#pragma unroll
  for (int i = 0; i < 4; ++i)
    gld_lds16(w1b + bofs + (u32)i * 64 * FF, lds + w * 1024 + i * 4096);
#pragma unroll
  for (int i = 0; i < 4; ++i)
    gld_lds16(w1b + bofs + (u32)i * 64 * FF + 32, lds + 16384 + w * 1024 + i * 4096);

#pragma unroll 2
  for (int ks = 0; ks < 16; ++ks) {
    // cvt A[ks] (compiler waits pa; that wait also drains older B[ks])
    bf16x8 av;
    {
      u32x4 p;
      p[0] = packbf2(asf(pa[0][0]), asf(pa[0][1]));
      p[1] = packbf2(asf(pa[0][2]), asf(pa[0][3]));
      p[2] = packbf2(asf(pa[1][0]), asf(pa[1][1]));
      p[3] = packbf2(asf(pa[1][2]), asf(pa[1][3]));
      av = *(bf16x8*)&p;
    }
    if (ks < 15) {
      pa[0] = ld4(xr + (u32)(ks + 1) * 32);
      pa[1] = ld4(xr + (u32)(ks + 1) * 32 + 4);
      // outstanding: B[ks](4,oldest) A[ks+1](2) B[ks+1](4) -> drain B[ks]
      asm volatile("s_waitcnt vmcnt(6)" ::: "memory");
    } else {
      asm volatile("s_waitcnt vmcnt(0)" ::: "memory");
    }
    __builtin_amdgcn_sched_barrier(0);
    __builtin_amdgcn_s_barrier();            // B[ks] visible to all waves
    __builtin_amdgcn_sched_barrier(0);

    const int bo = (ks & 1) * 16384;
#pragma unroll
    for (int n = 0; n < 16; ++n) {
      const bf16x8 bv = *(const bf16x8*)(lds + bo + bvb + n * 1024);
      acc[n] = __builtin_amdgcn_mfma_f32_16x16x32_bf16(bv, av, acc[n], 0, 0, 0);
    }
    __builtin_amdgcn_sched_barrier(0);
    __builtin_amdgcn_s_barrier();            // all waves done reading buf[ks&1]
    __builtin_amdgcn_sched_barrier(0);
    if (ks <= 13) {                          // refill buf[ks&1] with B[ks+2]
      unsigned char* bl = lds + bo + w * 1024;
#pragma unroll
      for (int i = 0; i < 4; ++i)
        gld_lds16(w1b + bofs + (u32)i * 64 * FF + (u32)(ks + 2) * 32, bl + i * 4096);
    }
  }

  // ---- epilogue via LDS: swizzled [64][256]bf16 tile (32KB, whole LDS) ----
  __syncthreads();   // all B reads/writes drained
  {
    const int zr = w * 16 + lr;              // 0..63, distinct per (w,lr)
#pragma unroll
    for (int n = 0; n < 16; ++n) {
      const int zc = n * 16 + kg * 4;        // 4 consecutive cols
      uint2 o;
      o.x = packbf2(acc[n][0], acc[n][1]);
      o.y = packbf2(acc[n][2], acc[n][3]);
      const int ch = zc >> 3;
      const int pch = (ch & 24) | ((ch ^ (zr & 7)) & 7);
      *(uint2*)(lds + zr * 512 + pch * 16 + (zc & 7) * 2) = o;
    }
  }
  __syncthreads();
  // dense store: 1KB contiguous per wave-instruction
#pragma unroll
  for (int i = 0; i < 8; ++i) {
    const int id = t + i * 256;
    const int rr = id >> 5, cc = id & 31;
    const int pch = (cc & 24) | ((cc ^ (rr & 7)) & 7);
    const uint4 v = *(const uint4*)(lds + rr * 512 + pch * 16);
    *(uint4*)(z + (u32)(rowBase + rr) * DD + cc * 8) = v;
  }
}

// ---------------------------------------------------------------- K2
// h1 = leaky((z[neigh1].sum + z)/6), only for rows layer 2 reads.
__global__ __launch_bounds__(256) void k2_agg1(
    const u16* __restrict__ z, const int* __restrict__ neigh1, u16* __restrict__ h1,
    const unsigned char* __restrict__ flags)
{
  const int t = threadIdx.x;
  const int row = blockIdx.x * 8 + (t >> 5);
  if (!flags[row]) return;   // half-wave uniform; no barriers in this kernel
  const int ch = t & 31;
  const u32 o0 = (u32)row * DD + ch * 8;
  uint4 a = *(const uint4*)(z + o0);
  float2 s0 = bf2f(a.x), s1 = bf2f(a.y), s2 = bf2f(a.z), s3 = bf2f(a.w);
#pragma unroll
  for (int j = 0; j < 5; ++j) {
    const int idx = neigh1[row * 5 + j];
    const uint4 v = *(const uint4*)(z + (u32)idx * DD + ch * 8);
    s0.x += bf_lo(v.x); s0.y += bf_hi(v.x);
    s1.x += bf_lo(v.y); s1.y += bf_hi(v.y);
    s2.x += bf_lo(v.z); s2.y += bf_hi(v.z);
    s3.x += bf_lo(v.w); s3.y += bf_hi(v.w);
  }
  const float sc = 1.0f / 6.0f;
  uint4 o;
  o.x = packbf2(lrelu(s0.x * sc), lrelu(s0.y * sc));
  o.y = packbf2(lrelu(s1.x * sc), lrelu(s1.y * sc));
  o.z = packbf2(lrelu(s2.x * sc), lrelu(s2.y * sc));
  o.w = packbf2(lrelu(s3.x * sc), lrelu(s3.y * sc));
  *(uint4*)(h1 + o0) = o;
}

// ---------------------------------------------------------------- K3 (fused layer2 + scores)
__global__ __launch_bounds__(512, 2) void k3_fused(
    const u16* __restrict__ h1, const u16* __restrict__ w2b, const u16* __restrict__ wcb,
    const int* __restrict__ nodes, const int* __restrict__ neigh2, float* __restrict__ out)
{
  // 0: A 8KB | 8192: B 32KB | 40960: Wc 24KB. After loop: 0..32KB = h2 tile.
  __shared__ __align__(16) unsigned char lds[65536];

  const int t = threadIdx.x;
  const int rowBase = blockIdx.x * 64;
  const int lane = t & 63, w = t >> 6;
  const int wm = w >> 2, wn = w & 3;
  const int lr = lane & 15, kg = lane >> 4;

#pragma unroll
  for (int i = 0; i < 3; ++i) {
    const int id = t + i * 512;
    uint4 v = make_uint4(0u, 0u, 0u, 0u);
    if (id < 1280) v = *(const uint4*)(wcb + (u32)id * 8);
    *(uint4*)(lds + 40960 + id * 16) = v;
  }

  const int r = t >> 3, c = t & 7;
  const int b = rowBase + r;
  u32 offA[11];
  offA[0] = (u32)nodes[b] * DD + (u32)c * 8;
#pragma unroll
  for (int j = 0; j < 10; ++j)
    offA[1 + j] = (u32)neigh2[b * 10 + j] * DD + (u32)c * 8;
  const int aW = swz(r, c);

  const u32 bofs = (u32)(w * 8 + (lane >> 3)) * DD + (u32)(lane & 7) * 8;
  unsigned char* bl0 = lds + 8192 + w * 1024;

  int aA[2][2], bA[2][4];
#pragma unroll
  for (int kk = 0; kk < 2; ++kk) {
    const int cb = kk * 4 + kg;
#pragma unroll
    for (int m = 0; m < 2; ++m) aA[kk][m] = swz(wm * 32 + m * 16 + lr, cb);
#pragma unroll
    for (int n = 0; n < 4; ++n) bA[kk][n] = 8192 + swz(wn * 64 + n * 16 + lr, cb);
  }

  f32x4 acc[2][4];
#pragma unroll
  for (int m = 0; m < 2; ++m)
#pragma unroll
    for (int n = 0; n < 4; ++n) acc[m][n] = (f32x4)0.0f;

  uint4 ag[11];
#pragma unroll
  for (int j = 0; j < 11; ++j) ag[j] = *(const uint4*)(h1 + offA[j]);

  for (int ks = 0; ks < 4; ++ks) {
    if (ks) __builtin_amdgcn_s_barrier();
    {
      float2 s0 = make_float2(0.f, 0.f), s1 = make_float2(0.f, 0.f);
      float2 s2 = make_float2(0.f, 0.f), s3 = make_float2(0.f, 0.f);
#pragma unroll
      for (int j = 0; j < 11; ++j) {
        s0.x += bf_lo(ag[j].x); s0.y += bf_hi(ag[j].x);
        s1.x += bf_lo(ag[j].y); s1.y += bf_hi(ag[j].y);
        s2.x += bf_lo(ag[j].z); s2.y += bf_hi(ag[j].z);
        s3.x += bf_lo(ag[j].w); s3.y += bf_hi(ag[j].w);
      }
      const float sc = 1.0f / 11.0f;
      uint4 o;
      o.x = packbf2(s0.x * sc, s0.y * sc);
      o.y = packbf2(s1.x * sc, s1.y * sc);
      o.z = packbf2(s2.x * sc, s2.y * sc);
      o.w = packbf2(s3.x * sc, s3.y * sc);
      *(uint4*)(lds + aW) = o;
    }
#pragma unroll
    for (int i = 0; i < 4; ++i)
      gld_lds16(w2b + bofs + (u32)i * 64 * DD + (u32)ks * 64, bl0 + i * 8192);
    __syncthreads();
    if (ks < 3) {
#pragma unroll
      for (int j = 0; j < 11; ++j)
        ag[j] = *(const uint4*)(h1 + offA[j] + (u32)(ks + 1) * 64);
    }
    __builtin_amdgcn_sched_barrier(0);
#pragma unroll
    for (int kk = 0; kk < 2; ++kk) {
      bf16x8 av[2], bv[4];
#pragma unroll
      for (int m = 0; m < 2; ++m) av[m] = *(const bf16x8*)(lds + aA[kk][m]);
#pragma unroll
      for (int n = 0; n < 4; ++n) bv[n] = *(const bf16x8*)(lds + bA[kk][n]);
#pragma unroll
      for (int m = 0; m < 2; ++m)
#pragma unroll
        for (int n = 0; n < 4; ++n)
          acc[m][n] = __builtin_amdgcn_mfma_f32_16x16x32_bf16(av[m], bv[n], acc[m][n], 0, 0, 0);
    }
  }

  __syncthreads();
#pragma unroll
  for (int m = 0; m < 2; ++m) {
#pragma unroll
    for (int j = 0; j < 4; ++j) {
      const int row = wm * 32 + m * 16 + kg * 4 + j;
#pragma unroll
      for (int n = 0; n < 4; ++n) {
        const int col = wn * 64 + n * 16 + lr;
        const int ch = col >> 3;
        const int pch = (ch & 24) | ((ch ^ row) & 7);
        *(u16*)(lds + row * 512 + pch * 16 + (col & 7) * 2) = fbits(lrelu(acc[m][n][j]));
      }
    }
  }
  __syncthreads();

  if (w < 4) {
    f32x4 acc2[3];
#pragma unroll
    for (int n = 0; n < 3; ++n) acc2[n] = (f32x4)0.0f;
    const int arow = w * 16 + lr;
#pragma unroll
    for (int ks2 = 0; ks2 < 8; ++ks2) {
      const int chb = ks2 * 4 + kg;
      const int pchA = (chb & 24) | ((chb ^ arow) & 7);
      const bf16x8 a = *(const bf16x8*)(lds + arow * 512 + pchA * 16);
#pragma unroll
      for (int n = 0; n < 3; ++n) {
        const int brow = n * 16 + lr;
        const int pchB = (chb & 24) | ((chb ^ brow) & 7);
        const bf16x8 bb = *(const bf16x8*)(lds + 40960 + brow * 512 + pchB * 16);
        acc2[n] = __builtin_amdgcn_mfma_f32_16x16x32_bf16(a, bb, acc2[n], 0, 0, 0);
      }
    }
#pragma unroll
    for (int n = 0; n < 3; ++n) {
      const int col = n * 16 + lr;
      if (col < CC) {
#pragma unroll
        for (int j = 0; j < 4; ++j) {
          const int rr = rowBase + w * 16 + kg * 4 + j;
          out[(u32)rr * CC + col] = acc2[n][j];
        }
      }
    }
  }
}

extern "C" void kernel_launch(void* const* d_in, const int* in_sizes, int n_in,
                              void* d_out, int out_size, void* d_ws, size_t ws_size,
                              hipStream_t stream) {
  const float* x    = (const float*)d_in[0];
  const float* W1   = (const float*)d_in[1];
  const float* W2   = (const float*)d_in[2];
  const float* Wc   = (const float*)d_in[3];
  const int* nodes  = (const int*)d_in[4];
  const int* neigh1 = (const int*)d_in[5];
  const int* neigh2 = (const int*)d_in[6];

  u16* z   = (u16*)d_ws;                     // 100096*256 bf16
  u16* h1  = z + (size_t)100096 * 256;       // 100096*256 bf16
  u16* w1b = h1 + (size_t)100096 * 256;      // 256x512 bf16 (4-chunk swizzled)
  u16* w2b = w1b + (size_t)256 * 512;        // 256x256 bf16 (8-chunk swizzled)
  u16* wcb = w2b + (size_t)256 * 256;        // 40x256 bf16 (8-chunk swizzled)
  u32* flagw = (u32*)(wcb + (size_t)40 * 256);  // 25024 u32 = 100096 flag bytes
  unsigned char* flags = (unsigned char*)flagw;

  k0_cvt<<<dim3(101), dim3(256), 0, stream>>>(W1, W2, Wc, w1b, w2b, wcb, flagw);
  k0b_flags<<<dim3(704), dim3(256), 0, stream>>>(nodes, neigh2, flags);
  k1_gemm<<<dim3(1563), dim3(256), 0, stream>>>(x, w1b, z);
  k2_agg1<<<dim3(12500), dim3(256), 0, stream>>>(z, neigh1, h1, flags);
  k3_fused<<<dim3(256), dim3(512), 0, stream>>>(h1, w2b, wcb, nodes, neigh2, (float*)d_out);
}

// Round 16
// 128.769 us; speedup vs baseline: 1.2070x; 1.2070x over previous
//
#include <hip/hip_runtime.h>
#include <hip/hip_bf16.h>

// SupervisedGraphSage forward. fp32 device buffers; bf16 MFMA internally.
//   z  = x @ W1^T                        [N, D]  (K1)
//   h1 = leaky((z[neigh1].sum + z)/6)    [N, D]  (K2, only referenced rows)
//   h2 = leaky((h1[neigh2].sum+h1[nodes])/11 @ W2^T); out = h2 @ Wc^T  (K3 fused)
//
// R16 = R14 champion (128.8us) + ONE register-neutral change: T5 s_setprio
// around K1's MFMA cluster. R15 lesson: this structure is register-capped at
// 16 waves/CU (acc[16]=64 AGPR; 128 total/wave = exactly 2x512-thr blocks/CU)
// — retiling cannot raise occupancy, and any +VGPR drops to 1 block/CU.
// R14's counted-vmcnt pipeline has wave phase-diversity -> T5's prerequisite.

#define NN 100000
#define FF 512
#define DD 256
#define BB 16384
#define CC 40

typedef __attribute__((ext_vector_type(8))) short bf16x8;
typedef __attribute__((ext_vector_type(4))) float f32x4;
typedef unsigned short u16;
typedef unsigned int u32;
typedef __attribute__((ext_vector_type(4))) u32 u32x4;

__device__ __forceinline__ float bf_lo(u32 u) { u32 v = u << 16; float f; __builtin_memcpy(&f, &v, 4); return f; }
__device__ __forceinline__ float bf_hi(u32 u) { u32 v = u & 0xffff0000u; float f; __builtin_memcpy(&f, &v, 4); return f; }
__device__ __forceinline__ float2 bf2f(u32 u) { return make_float2(bf_lo(u), bf_hi(u)); }
__device__ __forceinline__ float asf(u32 u) { float f; __builtin_memcpy(&f, &u, 4); return f; }
__device__ __forceinline__ u32 packbf2(float a, float b) {
  __hip_bfloat162 h = __float22bfloat162_rn(make_float2(a, b));
  u32 u; __builtin_memcpy(&u, &h, 4); return u;
}
__device__ __forceinline__ u16 fbits(float v) {
  __hip_bfloat16 h = __float2bfloat16(v);
  u16 u; __builtin_memcpy(&u, &h, 2); return u;
}
__device__ __forceinline__ float lrelu(float v) { return v >= 0.f ? v : 0.2f * v; }
// [R][64]-bf16 tile: byte offset of chunk c in row r, XOR-swizzled (G4).
__device__ __forceinline__ int swz(int r, int c) { return r * 128 + ((c ^ (r & 7)) << 4); }
// direct global->LDS 16B copy (dest = wave-uniform base + lane*16)
__device__ __forceinline__ void gld_lds16(const u16* g, void* l) {
  __builtin_amdgcn_global_load_lds((const __attribute__((address_space(1))) unsigned int*)g,
                                   (__attribute__((address_space(3))) unsigned int*)l, 16, 0, 0);
}
__device__ __forceinline__ u32x4 ld4(const float* p) { return *(const u32x4*)p; }

// ---------------------------------------------------------------- K0
// fp32 weights -> bf16, chunk-swizzled storage; also zero the h1-row flags.
__global__ __launch_bounds__(256) void k0_cvt(
    const float* __restrict__ W1, const float* __restrict__ W2, const float* __restrict__ Wc,
    u16* __restrict__ w1b, u16* __restrict__ w2b, u16* __restrict__ wcb,
    u32* __restrict__ flagw)
{
  const int i = blockIdx.x * 256 + threadIdx.x;
  if (i < 25024) flagw[i] = 0;   // 100096 flag bytes
  const float* src; u16* dst; int r, cc, rowE;
  if (i < 16384)      { src = W1; dst = w1b; r = i >> 6; cc = i & 63; rowE = 512; }
  else if (i < 24576) { int j = i - 16384; src = W2; dst = w2b; r = j >> 5; cc = j & 31; rowE = 256; }
  else if (i < 25856) { int j = i - 24576; src = Wc; dst = wcb; r = j >> 5; cc = j & 31; rowE = 256; }
  else return;
  const int g = cc >> 3, cp = cc & 7;
  const float* s = src + (u32)r * rowE + g * 64 + (u32)(cp ^ (r & 7)) * 8;
  const float4 v0 = *(const float4*)s;
  const float4 v1 = *(const float4*)(s + 4);
  uint4 o;
  o.x = packbf2(v0.x, v0.y); o.y = packbf2(v0.z, v0.w);
  o.z = packbf2(v1.x, v1.y); o.w = packbf2(v1.z, v1.w);
  *(uint4*)(dst + (u32)r * rowE + g * 64 + cp * 8) = o;
}

// ---------------------------------------------------------------- K0b
__global__ __launch_bounds__(256) void k0b_flags(
    const int* __restrict__ nodes, const int* __restrict__ neigh2,
    unsigned char* __restrict__ flags)
{
  const int i = blockIdx.x * 256 + threadIdx.x;
  int idx;
  if (i < BB) idx = nodes[i];
  else if (i < BB + BB * 10) idx = neigh2[i - BB];
  else return;
  flags[idx] = 1;
}

// ---------------------------------------------------------------- K1
// z = x @ W1^T. BM=128, BN=256, BK=64, 8 steps, 512 thr = 8 waves.
// Wave tile 16x256: wave w owns x-rows rowBase + w*16 + (lane&15), ALL cols.
// A: per-wave private, direct global loads (the MFMA fragment layout), cvt in
// regs. B: [256][64]bf16 LDS dbuf via gld_lds from pre-swizzled w1b, counted
// vmcnt(8). Barriers guard ONLY B. T5: setprio(1) around the MFMA cluster.
__global__ __launch_bounds__(512, 4) void k1_gemm(
    const float* __restrict__ x, const u16* __restrict__ w1b, u16* __restrict__ z)
{
  __shared__ __align__(16) unsigned char lds[65536];  // B0 @0, B1 @32768; epi reuses

  const int t = threadIdx.x;
  const int rowBase = blockIdx.x * 128;
  const int lane = t & 63, w = t >> 6;
  const int lr = lane & 15, kg = lane >> 4;

  // private A row for this lane (all n-frags share it)
  int rw = rowBase + w * 16 + lr; if (rw > NN - 1) rw = NN - 1;
  const float* xr = x + (u32)rw * FF + (u32)kg * 8;

  // B staging: 4 gld_lds/wave/step, rows w*8+(lane>>3)+i*64
  const u32 bofs = (u32)(w * 8 + (lane >> 3)) * FF + (u32)(lane & 7) * 8;

  // bv base byte-addrs: row = n*16+lr -> (row&7)=lr&7; phys chunk n-independent
  int bvb[2];
#pragma unroll
  for (int kk = 0; kk < 2; ++kk)
    bvb[kk] = lr * 128 + (((kk * 4 + kg) ^ (lr & 7)) << 4);

  f32x4 acc[16];
#pragma unroll
  for (int n = 0; n < 16; ++n) acc[n] = (f32x4)0.0f;

  // prologue: A[0] (4 loads), B[0] -> buf0, B[1] -> buf1
  u32x4 pa[2][2];
#pragma unroll
  for (int kk = 0; kk < 2; ++kk) {
    pa[kk][0] = ld4(xr + kk * 32);
    pa[kk][1] = ld4(xr + kk * 32 + 4);
  }
#pragma unroll
  for (int i = 0; i < 4; ++i)
    gld_lds16(w1b + bofs + (u32)i * 64 * FF, lds + w * 1024 + i * 8192);
#pragma unroll
  for (int i = 0; i < 4; ++i)
    gld_lds16(w1b + bofs + (u32)i * 64 * FF + 64, lds + 32768 + w * 1024 + i * 8192);

#pragma unroll
  for (int ks = 0; ks < 8; ++ks) {
    // cvt A[ks] (compiler waits pa loads)
    bf16x8 av[2];
#pragma unroll
    for (int kk = 0; kk < 2; ++kk) {
      u32x4 p;
      p[0] = packbf2(asf(pa[kk][0][0]), asf(pa[kk][0][1]));
      p[1] = packbf2(asf(pa[kk][0][2]), asf(pa[kk][0][3]));
      p[2] = packbf2(asf(pa[kk][1][0]), asf(pa[kk][1][1]));
      p[3] = packbf2(asf(pa[kk][1][2]), asf(pa[kk][1][3]));
      av[kk] = *(bf16x8*)&p;
    }
    if (ks < 7) {
      // issue A[ks+1]
#pragma unroll
      for (int kk = 0; kk < 2; ++kk) {
        pa[kk][0] = ld4(xr + (u32)(ks + 1) * 64 + kk * 32);
        pa[kk][1] = ld4(xr + (u32)(ks + 1) * 64 + kk * 32 + 4);
      }
      // keep A[ks+1](4)+B[ks+1](4); B[ks] drained
      asm volatile("s_waitcnt vmcnt(8)" ::: "memory");
    } else {
      asm volatile("s_waitcnt vmcnt(0)" ::: "memory");
    }
    __builtin_amdgcn_sched_barrier(0);
    __builtin_amdgcn_s_barrier();            // B[ks] visible to all waves
    __builtin_amdgcn_sched_barrier(0);

    const int bo = (ks & 1) * 32768;
    __builtin_amdgcn_s_setprio(1);           // T5: favor MFMA-issuing wave
#pragma unroll
    for (int kk = 0; kk < 2; ++kk)
#pragma unroll
      for (int n = 0; n < 16; ++n) {
        const bf16x8 bv = *(const bf16x8*)(lds + bo + bvb[kk] + n * 2048);
        acc[n] = __builtin_amdgcn_mfma_f32_16x16x32_bf16(bv, av[kk], acc[n], 0, 0, 0);
      }
    __builtin_amdgcn_s_setprio(0);
    __builtin_amdgcn_sched_barrier(0);
    __builtin_amdgcn_s_barrier();            // all waves done reading buf[ks&1]
    __builtin_amdgcn_sched_barrier(0);
    if (ks <= 5) {                           // refill buf[ks&1] with B[ks+2]
      unsigned char* bl = lds + bo + w * 1024;
#pragma unroll
      for (int i = 0; i < 4; ++i)
        gld_lds16(w1b + bofs + (u32)i * 64 * FF + (u32)(ks + 2) * 64, bl + i * 8192);
    }
  }

  // ---- epilogue via LDS: swizzled [128][256]bf16 tile @0 ----
  __syncthreads();   // all B reads/writes drained; whole LDS reusable
  {
    const int zr = w * 16 + lr;              // 0..127, distinct per (w,lr)
#pragma unroll
    for (int n = 0; n < 16; ++n) {
      const int zc = n * 16 + kg * 4;        // 4 consecutive cols
      uint2 o;
      o.x = packbf2(acc[n][0], acc[n][1]);
      o.y = packbf2(acc[n][2], acc[n][3]);
      const int ch = zc >> 3;
      const int pch = (ch & 24) | ((ch ^ (zr & 7)) & 7);
      *(uint2*)(lds + zr * 512 + pch * 16 + (zc & 7) * 2) = o;
    }
  }
  __syncthreads();
  // dense store: 32 lanes cover one 512B row; 1KB contiguous per instruction
#pragma unroll
  for (int i = 0; i < 8; ++i) {
    const int id = t + i * 512;
    const int rr = id >> 5, cc = id & 31;
    const int pch = (cc & 24) | ((cc ^ (rr & 7)) & 7);
    const uint4 v = *(const uint4*)(lds + rr * 512 + pch * 16);
    *(uint4*)(z + (u32)(rowBase + rr) * DD + cc * 8) = v;
  }
}

// ---------------------------------------------------------------- K2
// h1 = leaky((z[neigh1].sum + z)/6), only for rows layer 2 reads.
__global__ __launch_bounds__(256) void k2_agg1(
    const u16* __restrict__ z, const int* __restrict__ neigh1, u16* __restrict__ h1,
    const unsigned char* __restrict__ flags)
{
  const int t = threadIdx.x;
  const int row = blockIdx.x * 8 + (t >> 5);
  if (!flags[row]) return;   // half-wave uniform; no barriers in this kernel
  const int ch = t & 31;
  const u32 o0 = (u32)row * DD + ch * 8;
  uint4 a = *(const uint4*)(z + o0);
  float2 s0 = bf2f(a.x), s1 = bf2f(a.y), s2 = bf2f(a.z), s3 = bf2f(a.w);
#pragma unroll
  for (int j = 0; j < 5; ++j) {
    const int idx = neigh1[row * 5 + j];
    const uint4 v = *(const uint4*)(z + (u32)idx * DD + ch * 8);
    s0.x += bf_lo(v.x); s0.y += bf_hi(v.x);
    s1.x += bf_lo(v.y); s1.y += bf_hi(v.y);
    s2.x += bf_lo(v.z); s2.y += bf_hi(v.z);
    s3.x += bf_lo(v.w); s3.y += bf_hi(v.w);
  }
  const float sc = 1.0f / 6.0f;
  uint4 o;
  o.x = packbf2(lrelu(s0.x * sc), lrelu(s0.y * sc));
  o.y = packbf2(lrelu(s1.x * sc), lrelu(s1.y * sc));
  o.z = packbf2(lrelu(s2.x * sc), lrelu(s2.y * sc));
  o.w = packbf2(lrelu(s3.x * sc), lrelu(s3.y * sc));
  *(uint4*)(h1 + o0) = o;
}

// ---------------------------------------------------------------- K3 (fused layer2 + scores)
__global__ __launch_bounds__(512, 2) void k3_fused(
    const u16* __restrict__ h1, const u16* __restrict__ w2b, const u16* __restrict__ wcb,
    const int* __restrict__ nodes, const int* __restrict__ neigh2, float* __restrict__ out)
{
  // 0: A 8KB | 8192: B 32KB | 40960: Wc 24KB. After loop: 0..32KB = h2 tile.
  __shared__ __align__(16) unsigned char lds[65536];

  const int t = threadIdx.x;
  const int rowBase = blockIdx.x * 64;
  const int lane = t & 63, w = t >> 6;
  const int wm = w >> 2, wn = w & 3;
  const int lr = lane & 15, kg = lane >> 4;

#pragma unroll
  for (int i = 0; i < 3; ++i) {
    const int id = t + i * 512;
    uint4 v = make_uint4(0u, 0u, 0u, 0u);
    if (id < 1280) v = *(const uint4*)(wcb + (u32)id * 8);
    *(uint4*)(lds + 40960 + id * 16) = v;
  }

  const int r = t >> 3, c = t & 7;
  const int b = rowBase + r;
  u32 offA[11];
  offA[0] = (u32)nodes[b] * DD + (u32)c * 8;
#pragma unroll
  for (int j = 0; j < 10; ++j)
    offA[1 + j] = (u32)neigh2[b * 10 + j] * DD + (u32)c * 8;
  const int aW = swz(r, c);

  const u32 bofs = (u32)(w * 8 + (lane >> 3)) * DD + (u32)(lane & 7) * 8;
  unsigned char* bl0 = lds + 8192 + w * 1024;

  int aA[2][2], bA[2][4];
#pragma unroll
  for (int kk = 0; kk < 2; ++kk) {
    const int cb = kk * 4 + kg;
#pragma unroll
    for (int m = 0; m < 2; ++m) aA[kk][m] = swz(wm * 32 + m * 16 + lr, cb);
#pragma unroll
    for (int n = 0; n < 4; ++n) bA[kk][n] = 8192 + swz(wn * 64 + n * 16 + lr, cb);
  }

  f32x4 acc[2][4];
#pragma unroll
  for (int m = 0; m < 2; ++m)
#pragma unroll
    for (int n = 0; n < 4; ++n) acc[m][n] = (f32x4)0.0f;

  uint4 ag[11];
#pragma unroll
  for (int j = 0; j < 11; ++j) ag[j] = *(const uint4*)(h1 + offA[j]);

  for (int ks = 0; ks < 4; ++ks) {
    if (ks) __builtin_amdgcn_s_barrier();
    {
      float2 s0 = make_float2(0.f, 0.f), s1 = make_float2(0.f, 0.f);
      float2 s2 = make_float2(0.f, 0.f), s3 = make_float2(0.f, 0.f);
#pragma unroll
      for (int j = 0; j < 11; ++j) {
        s0.x += bf_lo(ag[j].x); s0.y += bf_hi(ag[j].x);
        s1.x += bf_lo(ag[j].y); s1.y += bf_hi(ag[j].y);
        s2.x += bf_lo(ag[j].z); s2.y += bf_hi(ag[j].z);
        s3.x += bf_lo(ag[j].w); s3.y += bf_hi(ag[j].w);
      }
      const float sc = 1.0f / 11.0f;
      uint4 o;
      o.x = packbf2(s0.x * sc, s0.y * sc);
      o.y = packbf2(s1.x * sc, s1.y * sc);
      o.z = packbf2(s2.x * sc, s2.y * sc);
      o.w = packbf2(s3.x * sc, s3.y * sc);
      *(uint4*)(lds + aW) = o;
    }
#pragma unroll
    for (int i = 0; i < 4; ++i)
      gld_lds16(w2b + bofs + (u32)i * 64 * DD + (u32)ks * 64, bl0 + i * 8192);
    __syncthreads();
    if (ks < 3) {
#pragma unroll
      for (int j = 0; j < 11; ++j)
        ag[j] = *(const uint4*)(h1 + offA[j] + (u32)(ks + 1) * 64);
    }
    __builtin_amdgcn_sched_barrier(0);
#pragma unroll
    for (int kk = 0; kk < 2; ++kk) {
      bf16x8 av[2], bv[4];
#pragma unroll
      for (int m = 0; m < 2; ++m) av[m] = *(const bf16x8*)(lds + aA[kk][m]);
#pragma unroll
      for (int n = 0; n < 4; ++n) bv[n] = *(const bf16x8*)(lds + bA[kk][n]);
#pragma unroll
      for (int m = 0; m < 2; ++m)
#pragma unroll
        for (int n = 0; n < 4; ++n)
          acc[m][n] = __builtin_amdgcn_mfma_f32_16x16x32_bf16(av[m], bv[n], acc[m][n], 0, 0, 0);
    }
  }

  __syncthreads();
#pragma unroll
  for (int m = 0; m < 2; ++m) {
#pragma unroll
    for (int j = 0; j < 4; ++j) {
      const int row = wm * 32 + m * 16 + kg * 4 + j;
#pragma unroll
      for (int n = 0; n < 4; ++n) {
        const int col = wn * 64 + n * 16 + lr;
        const int ch = col >> 3;
        const int pch = (ch & 24) | ((ch ^ row) & 7);
        *(u16*)(lds + row * 512 + pch * 16 + (col & 7) * 2) = fbits(lrelu(acc[m][n][j]));
      }
    }
  }
  __syncthreads();

  if (w < 4) {
    f32x4 acc2[3];
#pragma unroll
    for (int n = 0; n < 3; ++n) acc2[n] = (f32x4)0.0f;
    const int arow = w * 16 + lr;
#pragma unroll
    for (int ks2 = 0; ks2 < 8; ++ks2) {
      const int chb = ks2 * 4 + kg;
      const int pchA = (chb & 24) | ((chb ^ arow) & 7);
      const bf16x8 a = *(const bf16x8*)(lds + arow * 512 + pchA * 16);
#pragma unroll
      for (int n = 0; n < 3; ++n) {
        const int brow = n * 16 + lr;
        const int pchB = (chb & 24) | ((chb ^ brow) & 7);
        const bf16x8 bb = *(const bf16x8*)(lds + 40960 + brow * 512 + pchB * 16);
        acc2[n] = __builtin_amdgcn_mfma_f32_16x16x32_bf16(a, bb, acc2[n], 0, 0, 0);
      }
    }
#pragma unroll
    for (int n = 0; n < 3; ++n) {
      const int col = n * 16 + lr;
      if (col < CC) {
#pragma unroll
        for (int j = 0; j < 4; ++j) {
          const int rr = rowBase + w * 16 + kg * 4 + j;
          out[(u32)rr * CC + col] = acc2[n][j];
        }
      }
    }
  }
}

extern "C" void kernel_launch(void* const* d_in, const int* in_sizes, int n_in,
                              void* d_out, int out_size, void* d_ws, size_t ws_size,
                              hipStream_t stream) {
  const float* x    = (const float*)d_in[0];
  const float* W1   = (const float*)d_in[1];
  const float* W2   = (const float*)d_in[2];
  const float* Wc   = (const float*)d_in[3];
  const int* nodes  = (const int*)d_in[4];
  const int* neigh1 = (const int*)d_in[5];
  const int* neigh2 = (const int*)d_in[6];

  u16* z   = (u16*)d_ws;                     // 100096*256 bf16
  u16* h1  = z + (size_t)100096 * 256;       // 100096*256 bf16
  u16* w1b = h1 + (size_t)100096 * 256;      // 256x512 bf16 (chunk-swizzled)
  u16* w2b = w1b + (size_t)256 * 512;        // 256x256 bf16 (chunk-swizzled)
  u16* wcb = w2b + (size_t)256 * 256;        // 40x256 bf16 (chunk-swizzled)
  u32* flagw = (u32*)(wcb + (size_t)40 * 256);  // 25024 u32 = 100096 flag bytes
  unsigned char* flags = (unsigned char*)flagw;

  k0_cvt<<<dim3(101), dim3(256), 0, stream>>>(W1, W2, Wc, w1b, w2b, wcb, flagw);
  k0b_flags<<<dim3(704), dim3(256), 0, stream>>>(nodes, neigh2, flags);
  k1_gemm<<<dim3(782), dim3(512), 0, stream>>>(x, w1b, z);
  k2_agg1<<<dim3(12500), dim3(256), 0, stream>>>(z, neigh1, h1, flags);
  k3_fused<<<dim3(256), dim3(512), 0, stream>>>(h1, w2b, wcb, nodes, neigh2, (float*)d_out);
}